// Round 8
// baseline (1002.291 us; speedup 1.0000x reference)
//
#include <hip/hip_runtime.h>

#define H 128
#define MB 64          // edges (or nodes) per block
#define LDB 136        // LDS row stride for [64 x 128] tiles (+8 pad)

typedef __attribute__((ext_vector_type(8))) short bf16x8;
typedef __attribute__((ext_vector_type(4))) short s16x4;
typedef __attribute__((ext_vector_type(4))) float f32x4;
typedef __attribute__((ext_vector_type(4))) float fv4;     // clang vec for nontemporal
typedef __attribute__((ext_vector_type(8))) unsigned short u16x8;

__device__ __forceinline__ short f2bf(float f) {
    union { float f; unsigned u; } v; v.f = f;
    unsigned r = v.u + 0x7FFF + ((v.u >> 16) & 1);   // RTNE
    return (short)(r >> 16);
}
__device__ __forceinline__ float bf2f(short s) {
    union { unsigned u; float f; } v;
    v.u = ((unsigned)(unsigned short)s) << 16;
    return v.f;
}
__device__ __forceinline__ unsigned short f2h(float f) {
    union { _Float16 h; unsigned short u; } c;
    c.h = (_Float16)f;                               // v_cvt_f16_f32 (RTNE)
    return c.u;
}
__device__ __forceinline__ float h2f(unsigned short u) {
    union { unsigned short u; _Float16 h; } c;
    c.u = u;
    return (float)c.h;                               // v_cvt_f32_f16
}

// block barrier with LDS-only drain; global loads/atomics stay in flight.
__device__ __forceinline__ void light_bar() {
    asm volatile("s_waitcnt lgkmcnt(0)" ::: "memory");
    __builtin_amdgcn_s_barrier();
    __builtin_amdgcn_sched_barrier(0);
}

// ---------------- weight prep: fp32 [K,N] -> bf16 transposed [N,K] ----------------
__global__ __launch_bounds__(256) void prep_weights(
    const float* __restrict__ W1, const float* __restrict__ W2,
    const float* __restrict__ WL,
    short* __restrict__ W1T, short* __restrict__ W2T, short* __restrict__ WLT)
{
    int tid = blockIdx.x * 256 + threadIdx.x;      // 0..32767
    {   // W1: [256,128] -> W1T [128][256]
        int n = tid >> 8, k = tid & 255;
        W1T[n * 256 + k] = f2bf(W1[k * 128 + n]);
    }
    if (tid < 16384) {  // W2, W_lift: [128,128] -> [128][128]
        int n = tid >> 7, k = tid & 127;
        W2T[n * 128 + k] = f2bf(W2[k * 128 + n]);
        WLT[n * 128 + k] = f2bf(WL[k * 128 + n]);
    }
}

// ---------------- node_rep fp32 -> bf16 copy (halves gather traffic) ----------------
__global__ __launch_bounds__(256) void node_prep(
    const float* __restrict__ node_rep, short* __restrict__ NRB, int total8)
{
    int i = blockIdx.x * 256 + threadIdx.x;        // one per 8 elems
    if (i < total8) {
        const fv4* p = (const fv4*)(node_rep + (size_t)i * 8);
        fv4 a = __builtin_nontemporal_load(p);
        fv4 b = __builtin_nontemporal_load(p + 1);
        bf16x8 o = { f2bf(a.x), f2bf(a.y), f2bf(a.z), f2bf(a.w),
                     f2bf(b.x), f2bf(b.y), f2bf(b.z), f2bf(b.w) };
        *(bf16x8*)(NRB + (size_t)i * 8) = o;
    }
}

// ---------------- edge kernel: single 18KB LDS tile, 5 light phases ----------------
// P1: stage lift=NRB[src]+NRB[dst].  P2: acc=lift@W1top, accR=lift@WL.
// P3: overwrite tile with er.        P4: acc+=er@W1bot -> h=relu; scatter pk-f16;
//                                        h overwrites tile.
// P5: edge_out = relu(e2*(h@WL) + accR)   [ = relu((e2*h+lift)@WL) ]
__global__ __launch_bounds__(256, 5) void edge_kernel(
    const short* __restrict__ NRB, const float* __restrict__ edge_rep,
    const int* __restrict__ eidx,
    const short* __restrict__ W1T, const short* __restrict__ WLT,
    const float* __restrict__ eps2p,
    unsigned short* __restrict__ lvl, float* __restrict__ edge_out, int E)
{
    __shared__ short sA[MB * LDB];   // [64][128] bf16: lift -> er -> h
    __shared__ int sSrc[MB], sDst[MB];

    const int tid = threadIdx.x;
    const int e0  = blockIdx.x * MB;
    const float e2 = 1.f + eps2p[0];

    const int row  = tid >> 2;            // staging role: 4 threads per edge row
    const int cseg = (tid & 3) << 5;      // 0,32,64,96

    // ---- P1: stage lift (NRB gather; NRB stays cache-resident: no nt) ----
    {
        int e = e0 + row;
        int ec = (e < E) ? e : (E - 1);
        int sI = eidx[ec], dI = eidx[E + ec];
        if ((tid & 3) == 0) { sSrc[row] = sI; sDst[row] = dI; }
        const bf16x8* sp = (const bf16x8*)(NRB + (size_t)sI * H + cseg);
        const bf16x8* dp = (const bf16x8*)(NRB + (size_t)dI * H + cseg);
        short* rowA = sA + row * LDB;
        #pragma unroll
        for (int j = 0; j < 4; ++j) {
            bf16x8 a = sp[j], b = dp[j];
            bf16x8 lift;
            #pragma unroll
            for (int t = 0; t < 8; ++t)
                lift[t] = f2bf(bf2f(a[t]) + bf2f(b[t]));
            *(bf16x8*)&rowA[cseg + 8 * j] = lift;
        }
    }
    light_bar();

    const int wave = tid >> 6;
    const int lane = tid & 63;
    const int m = lane & 15;              // A row / B col / D col
    const int q = lane >> 4;              // k-quad / D row group
    const f32x4 zero = {0.f, 0.f, 0.f, 0.f};

    // ---- P2: acc = lift@W1_top, accR = lift@WL (shared A fragments) ----
    f32x4 acc[4][2], accR[4][2];
    #pragma unroll
    for (int mt = 0; mt < 4; ++mt)
        #pragma unroll
        for (int nt = 0; nt < 2; ++nt) { acc[mt][nt] = zero; accR[mt][nt] = zero; }

    #pragma unroll
    for (int ks = 0; ks < 4; ++ks) {
        int k0 = ks * 32 + q * 8;
        bf16x8 aF[4];
        #pragma unroll
        for (int mt = 0; mt < 4; ++mt)
            aF[mt] = *(const bf16x8*)&sA[(mt * 16 + m) * LDB + k0];
        #pragma unroll
        for (int nt = 0; nt < 2; ++nt) {
            int n = (wave << 5) + (nt << 4) + m;
            bf16x8 bP = *(const bf16x8*)&W1T[n * 256 + k0];        // W1 top half
            bf16x8 bR = *(const bf16x8*)&WLT[n * 128 + k0];
            #pragma unroll
            for (int mt = 0; mt < 4; ++mt) {
                acc[mt][nt]  = __builtin_amdgcn_mfma_f32_16x16x32_bf16(
                    aF[mt], bP, acc[mt][nt], 0, 0, 0);
                accR[mt][nt] = __builtin_amdgcn_mfma_f32_16x16x32_bf16(
                    aF[mt], bR, accR[mt][nt], 0, 0, 0);
            }
        }
    }
    light_bar();                          // all lift reads done

    // ---- P3: overwrite tile with er (nt stream) ----
    {
        int e = e0 + row;
        int ec = (e < E) ? e : (E - 1);
        const fv4* ep = (const fv4*)(edge_rep + (size_t)ec * H + cseg);
        short* rowA = sA + row * LDB;
        #pragma unroll
        for (int j = 0; j < 4; ++j) {
            fv4 c0 = __builtin_nontemporal_load(ep + 2 * j);
            fv4 c1 = __builtin_nontemporal_load(ep + 2 * j + 1);
            bf16x8 er = { f2bf(c0.x), f2bf(c0.y), f2bf(c0.z), f2bf(c0.w),
                          f2bf(c1.x), f2bf(c1.y), f2bf(c1.z), f2bf(c1.w) };
            *(bf16x8*)&rowA[cseg + 8 * j] = er;
        }
    }
    light_bar();

    // ---- P4: acc += er@W1_bottom ----
    #pragma unroll
    for (int ks = 0; ks < 4; ++ks) {
        int k0 = ks * 32 + q * 8;
        bf16x8 aF[4];
        #pragma unroll
        for (int mt = 0; mt < 4; ++mt)
            aF[mt] = *(const bf16x8*)&sA[(mt * 16 + m) * LDB + k0];
        bf16x8 bF[2];
        #pragma unroll
        for (int nt = 0; nt < 2; ++nt) {
            int n = (wave << 5) + (nt << 4) + m;
            bF[nt] = *(const bf16x8*)&W1T[n * 256 + 128 + k0];     // bottom half
        }
        #pragma unroll
        for (int mt = 0; mt < 4; ++mt)
            #pragma unroll
            for (int nt = 0; nt < 2; ++nt)
                acc[mt][nt] = __builtin_amdgcn_mfma_f32_16x16x32_bf16(
                    aF[mt], bF[nt], acc[mt][nt], 0, 0, 0);
    }
    light_bar();                          // all er reads done before h overwrite

    // ---- epilogue: h = relu(acc); h -> tile (in place); pk-f16 scatter ----
    #pragma unroll
    for (int mt = 0; mt < 4; ++mt) {
        #pragma unroll
        for (int nt = 0; nt < 2; ++nt) {
            int col = (wave << 5) + (nt << 4) + m;
            #pragma unroll
            for (int i = 0; i < 4; ++i) {
                int rr = (mt << 4) + (q << 2) + i;
                float h = acc[mt][nt][i];
                h = h > 0.f ? h : 0.f;
                float hp = __shfl_xor(h, 1);
                if ((m & 1) == 0) {
                    unsigned hb = (unsigned)(unsigned short)f2bf(h)
                                | ((unsigned)(unsigned short)f2bf(hp) << 16);
                    *(unsigned*)&sA[rr * LDB + col] = hb;          // h in place
                    if (e0 + rr < E) {
                        unsigned pk = (unsigned)f2h(h) | ((unsigned)f2h(hp) << 16);
                        int sn = sSrc[rr], dn = sDst[rr];
                        unsigned long long a0 =
                            (unsigned long long)(lvl + (size_t)sn * H + col);
                        unsigned long long a1 =
                            (unsigned long long)(lvl + (size_t)dn * H + col);
                        asm volatile("global_atomic_pk_add_f16 %0, %1, off"
                                     :: "v"(a0), "v"(pk) : "memory");
                        asm volatile("global_atomic_pk_add_f16 %0, %1, off"
                                     :: "v"(a1), "v"(pk) : "memory");
                    }
                }
            }
        }
    }
    light_bar();                          // h tile visible (atomics keep flying)

    // ---- P5: edge_out = relu(e2*(h@WL) + accR) ----
    f32x4 acc2[4][2];
    #pragma unroll
    for (int mt = 0; mt < 4; ++mt)
        #pragma unroll
        for (int nt = 0; nt < 2; ++nt) acc2[mt][nt] = zero;

    #pragma unroll
    for (int ks = 0; ks < 4; ++ks) {
        int k0 = ks * 32 + q * 8;
        bf16x8 aF[4];
        #pragma unroll
        for (int mt = 0; mt < 4; ++mt)
            aF[mt] = *(const bf16x8*)&sA[(mt * 16 + m) * LDB + k0];
        bf16x8 bF[2];
        #pragma unroll
        for (int nt = 0; nt < 2; ++nt) {
            int n = (wave << 5) + (nt << 4) + m;
            bF[nt] = *(const bf16x8*)&WLT[n * 128 + k0];
        }
        #pragma unroll
        for (int mt = 0; mt < 4; ++mt)
            #pragma unroll
            for (int nt = 0; nt < 2; ++nt)
                acc2[mt][nt] = __builtin_amdgcn_mfma_f32_16x16x32_bf16(
                    aF[mt], bF[nt], acc2[mt][nt], 0, 0, 0);
    }

    #pragma unroll
    for (int mt = 0; mt < 4; ++mt) {
        #pragma unroll
        for (int nt = 0; nt < 2; ++nt) {
            int col = (wave << 5) + (nt << 4) + m;
            #pragma unroll
            for (int i = 0; i < 4; ++i) {
                int rr = (mt << 4) + (q << 2) + i;
                if (e0 + rr < E) {
                    float v = e2 * acc2[mt][nt][i] + accR[mt][nt][i];
                    v = v > 0.f ? v : 0.f;
                    __builtin_nontemporal_store(v, &edge_out[(size_t)(e0 + rr) * H + col]);
                }
            }
        }
    }
}

// ---------------- node kernel ----------------
// node_out = relu(((1+eps1)*node_rep_bf16 + lvl_fp16) @ W2)
__global__ __launch_bounds__(256) void node_kernel(
    const short* __restrict__ NRB, const unsigned short* __restrict__ lvl,
    const short* __restrict__ W2T, const float* __restrict__ eps1p,
    float* __restrict__ node_out, int N)
{
    __shared__ short sA[MB * LDB];

    const int tid = threadIdx.x;
    const int r0  = blockIdx.x * MB;
    const float e1 = 1.f + eps1p[0];

    {
        int row  = tid >> 2;
        int cseg = (tid & 3) << 5;
        int r = r0 + row;
        short* rowA = sA + row * LDB;
        if (r < N) {
            const bf16x8* np = (const bf16x8*)(NRB + (size_t)r * H + cseg);
            const uint2* lp = (const uint2*)(lvl + (size_t)r * H + cseg);
            #pragma unroll
            for (int j = 0; j < 4; ++j) {
                bf16x8 nb = np[j];
                uint2 h0 = lp[2 * j], h1 = lp[2 * j + 1];
                float f[8] = {
                    h2f((unsigned short)(h0.x & 0xFFFF)), h2f((unsigned short)(h0.x >> 16)),
                    h2f((unsigned short)(h0.y & 0xFFFF)), h2f((unsigned short)(h0.y >> 16)),
                    h2f((unsigned short)(h1.x & 0xFFFF)), h2f((unsigned short)(h1.x >> 16)),
                    h2f((unsigned short)(h1.y & 0xFFFF)), h2f((unsigned short)(h1.y >> 16)) };
                bf16x8 o;
                #pragma unroll
                for (int t = 0; t < 8; ++t)
                    o[t] = f2bf(e1 * bf2f(nb[t]) + f[t]);
                *(bf16x8*)&rowA[cseg + 8 * j] = o;
            }
        } else {
            s16x4 z = {0, 0, 0, 0};
            #pragma unroll
            for (int j = 0; j < 8; ++j) *(s16x4*)&rowA[cseg + 4 * j] = z;
        }
    }
    __syncthreads();

    const int wave = tid >> 6;
    const int lane = tid & 63;
    const int m = lane & 15;
    const int q = lane >> 4;

    f32x4 zero = {0.f, 0.f, 0.f, 0.f};
    f32x4 acc[4][2];
    #pragma unroll
    for (int mt = 0; mt < 4; ++mt)
        #pragma unroll
        for (int nt = 0; nt < 2; ++nt) acc[mt][nt] = zero;

    #pragma unroll
    for (int ks = 0; ks < 4; ++ks) {
        int k0 = ks * 32 + q * 8;
        bf16x8 aF[4];
        #pragma unroll
        for (int mt = 0; mt < 4; ++mt)
            aF[mt] = *(const bf16x8*)&sA[(mt * 16 + m) * LDB + k0];
        bf16x8 bF[2];
        #pragma unroll
        for (int nt = 0; nt < 2; ++nt) {
            int n = (wave << 5) + (nt << 4) + m;
            bF[nt] = *(const bf16x8*)&W2T[n * 128 + k0];
        }
        #pragma unroll
        for (int mt = 0; mt < 4; ++mt)
            #pragma unroll
            for (int nt = 0; nt < 2; ++nt)
                acc[mt][nt] = __builtin_amdgcn_mfma_f32_16x16x32_bf16(
                    aF[mt], bF[nt], acc[mt][nt], 0, 0, 0);
    }

    #pragma unroll
    for (int mt = 0; mt < 4; ++mt) {
        #pragma unroll
        for (int nt = 0; nt < 2; ++nt) {
            int col = (wave << 5) + (nt << 4) + m;
            #pragma unroll
            for (int i = 0; i < 4; ++i) {
                int rr = (mt << 4) + (q << 2) + i;
                if (r0 + rr < N) {
                    float v = acc[mt][nt][i];
                    v = v > 0.f ? v : 0.f;
                    __builtin_nontemporal_store(v, &node_out[(size_t)(r0 + rr) * H + col]);
                }
            }
        }
    }
}

extern "C" void kernel_launch(void* const* d_in, const int* in_sizes, int n_in,
                              void* d_out, int out_size, void* d_ws, size_t ws_size,
                              hipStream_t stream) {
    const float* node_rep = (const float*)d_in[0];
    const float* edge_rep = (const float*)d_in[1];
    const int*   eidx     = (const int*)d_in[2];
    const float* W1       = (const float*)d_in[3];
    const float* W2       = (const float*)d_in[4];
    const float* WL       = (const float*)d_in[5];
    const float* eps1     = (const float*)d_in[6];
    const float* eps2     = (const float*)d_in[7];

    const int N = in_sizes[0] / H;     // 50000
    const int E = in_sizes[1] / H;     // 800000

    float* node_out = (float*)d_out;
    float* edge_out = (float*)d_out + (size_t)N * H;

    // workspace: bf16 weights (128 KB) + fp16 lvl (12.8 MB) + bf16 node_rep (12.8 MB)
    char* ws = (char*)d_ws;
    short* W1T = (short*)ws;                               // 256*128*2 = 64 KB
    short* W2T = (short*)(ws + 65536);                     // 32 KB
    short* WLT = (short*)(ws + 65536 + 32768);             // 32 KB
    unsigned short* lvl = (unsigned short*)(ws + 131072);  // N*H*2 = 12.8 MB
    short* NRB = (short*)(ws + 131072 + (size_t)N * H * 2);

    const int total8 = N * H / 8;      // 800000

    hipMemsetAsync(lvl, 0, (size_t)N * H * sizeof(unsigned short), stream);
    prep_weights<<<128, 256, 0, stream>>>(W1, W2, WL, W1T, W2T, WLT);
    node_prep<<<(total8 + 255) / 256, 256, 0, stream>>>(node_rep, NRB, total8);
    edge_kernel<<<(E + MB - 1) / MB, 256, 0, stream>>>(
        NRB, edge_rep, eidx, W1T, WLT, eps2, lvl, edge_out, E);
    node_kernel<<<(N + MB - 1) / MB, 256, 0, stream>>>(
        NRB, lvl, W2T, eps1, node_out, N);
}

// Round 9
// 827.238 us; speedup vs baseline: 1.2116x; 1.2116x over previous
//
#include <hip/hip_runtime.h>

#define H 128
#define MB 64          // edges (or nodes) per block
#define LDA 264        // LDS row stride (elems) for the [64 x 256] concat tile (+8 pad)
#define LDB 136        // LDS row stride for [64 x 128] tiles (+8 pad)

typedef __attribute__((ext_vector_type(8))) short bf16x8;
typedef __attribute__((ext_vector_type(4))) short s16x4;
typedef __attribute__((ext_vector_type(4))) float f32x4;
typedef __attribute__((ext_vector_type(4))) float fv4;     // clang vec for nontemporal

__device__ __forceinline__ short f2bf(float f) {
    union { float f; unsigned u; } v; v.f = f;
    unsigned r = v.u + 0x7FFF + ((v.u >> 16) & 1);   // RTNE
    return (short)(r >> 16);
}
__device__ __forceinline__ float bf2f(short s) {
    union { unsigned u; float f; } v;
    v.u = ((unsigned)(unsigned short)s) << 16;
    return v.f;
}
__device__ __forceinline__ unsigned short f2h(float f) {
    union { _Float16 h; unsigned short u; } c;
    c.h = (_Float16)f;                               // v_cvt_f16_f32 (RTNE)
    return c.u;
}
__device__ __forceinline__ float h2f(unsigned short u) {
    union { unsigned short u; _Float16 h; } c;
    c.u = u;
    return (float)c.h;                               // v_cvt_f32_f16
}

// block barrier with LDS-only drain: global loads and atomics stay in flight
// across it (per-thread data deps still get compiler-inserted vmcnt waits).
__device__ __forceinline__ void light_bar() {
    asm volatile("s_waitcnt lgkmcnt(0)" ::: "memory");
    __builtin_amdgcn_s_barrier();
    __builtin_amdgcn_sched_barrier(0);
}

// ---------------- weight prep: fp32 [K,N] -> bf16 transposed [N,K] ----------------
__global__ __launch_bounds__(256) void prep_weights(
    const float* __restrict__ W1, const float* __restrict__ W2,
    const float* __restrict__ WL,
    short* __restrict__ W1T, short* __restrict__ W2T, short* __restrict__ WLT)
{
    int tid = blockIdx.x * 256 + threadIdx.x;      // 0..32767
    {   // W1: [256,128] -> W1T [128][256]
        int n = tid >> 8, k = tid & 255;
        W1T[n * 256 + k] = f2bf(W1[k * 128 + n]);
    }
    if (tid < 16384) {  // W2, W_lift: [128,128] -> [128][128]
        int n = tid >> 7, k = tid & 127;
        W2T[n * 128 + k] = f2bf(W2[k * 128 + n]);
        WLT[n * 128 + k] = f2bf(WL[k * 128 + n]);
    }
}

// ---------------- node_rep fp32 -> bf16 copy (halves gather traffic) ----------------
__global__ __launch_bounds__(256) void node_prep(
    const float* __restrict__ node_rep, short* __restrict__ NRB, int total8)
{
    int i = blockIdx.x * 256 + threadIdx.x;        // one per 8 elems
    if (i < total8) {
        const fv4* p = (const fv4*)(node_rep + (size_t)i * 8);
        fv4 a = __builtin_nontemporal_load(p);
        fv4 b = __builtin_nontemporal_load(p + 1);
        bf16x8 o = { f2bf(a.x), f2bf(a.y), f2bf(a.z), f2bf(a.w),
                     f2bf(b.x), f2bf(b.y), f2bf(b.z), f2bf(b.w) };
        *(bf16x8*)(NRB + (size_t)i * 8) = o;
    }
}

// ---------------- edge kernel (r3 structure + early scatter + light barriers) ----
// GEMM1: [64,256]x[256,128] -> h; epilogue writes b2 into the dead edge_rep half
// of sA AND issues the pk-f16 atomic scatter (stays in flight across light_bar,
// drains under GEMM2/stores/other blocks); GEMM2 -> edge_out.
__global__ __launch_bounds__(256) void edge_kernel(
    const short* __restrict__ NRB, const float* __restrict__ edge_rep,
    const int* __restrict__ eidx,
    const short* __restrict__ W1T, const short* __restrict__ WLT,
    const float* __restrict__ eps2p,
    unsigned short* __restrict__ lvl, float* __restrict__ edge_out, int E)
{
    __shared__ short sA[MB * LDA];   // [64][256]: cols 0..127 lift, 128..255 er -> b2
    __shared__ int sSrc[MB], sDst[MB];

    const int tid = threadIdx.x;
    const int e0  = blockIdx.x * MB;
    const float e2 = 1.f + eps2p[0];

    // ---- stage: 4 threads per edge row, each covers 32 cols ----
    {
        int row  = tid >> 2;
        int cseg = (tid & 3) << 5;        // 0,32,64,96
        int e = e0 + row;
        int ec = (e < E) ? e : (E - 1);
        int sIdx = eidx[ec], dIdx = eidx[E + ec];
        if ((tid & 3) == 0) { sSrc[row] = sIdx; sDst[row] = dIdx; }
        short* rowA = sA + row * LDA;
        const bf16x8* sp = (const bf16x8*)(NRB + (size_t)sIdx * H + cseg);
        const bf16x8* dp = (const bf16x8*)(NRB + (size_t)dIdx * H + cseg);
        const fv4* ep = (const fv4*)(edge_rep + (size_t)ec * H + cseg);
        #pragma unroll
        for (int j = 0; j < 4; ++j) {
            bf16x8 a = sp[j], b = dp[j];
            bf16x8 lift;
            #pragma unroll
            for (int t = 0; t < 8; ++t)
                lift[t] = f2bf(bf2f(a[t]) + bf2f(b[t]));
            *(bf16x8*)&rowA[cseg + 8 * j] = lift;
        }
        #pragma unroll
        for (int j = 0; j < 4; ++j) {
            fv4 c0 = __builtin_nontemporal_load(ep + 2 * j);
            fv4 c1 = __builtin_nontemporal_load(ep + 2 * j + 1);
            bf16x8 er = { f2bf(c0.x), f2bf(c0.y), f2bf(c0.z), f2bf(c0.w),
                          f2bf(c1.x), f2bf(c1.y), f2bf(c1.z), f2bf(c1.w) };
            *(bf16x8*)&rowA[H + cseg + 8 * j] = er;
        }
    }
    light_bar();

    const int wave = tid >> 6;
    const int lane = tid & 63;
    const int m = lane & 15;     // A row / B col / D col
    const int q = lane >> 4;     // k-quad, D row group

    // ---- GEMM1: wave owns cols [wave*32, wave*32+32), all 64 rows ----
    f32x4 zero = {0.f, 0.f, 0.f, 0.f};
    f32x4 acc[4][2];
    #pragma unroll
    for (int mt = 0; mt < 4; ++mt)
        #pragma unroll
        for (int nt = 0; nt < 2; ++nt) acc[mt][nt] = zero;

    #pragma unroll
    for (int ks = 0; ks < 8; ++ks) {
        int k0 = ks * 32 + q * 8;
        bf16x8 aF[4];
        #pragma unroll
        for (int mt = 0; mt < 4; ++mt)
            aF[mt] = *(const bf16x8*)&sA[(mt * 16 + m) * LDA + k0];
        bf16x8 bF[2];
        #pragma unroll
        for (int nt = 0; nt < 2; ++nt) {
            int n = (wave << 5) + (nt << 4) + m;
            bF[nt] = *(const bf16x8*)&W1T[n * 256 + k0];
        }
        #pragma unroll
        for (int mt = 0; mt < 4; ++mt)
            #pragma unroll
            for (int nt = 0; nt < 2; ++nt)
                acc[mt][nt] = __builtin_amdgcn_mfma_f32_16x16x32_bf16(
                    aF[mt], bF[nt], acc[mt][nt], 0, 0, 0);
    }
    light_bar();   // GEMM1 reads of cols 128..255 done before b2 overwrites them

    // ---- epilogue 1: relu -> h; b2 into sA cols 128..255; EARLY pk-f16 scatter ----
    #pragma unroll
    for (int mt = 0; mt < 4; ++mt) {
        #pragma unroll
        for (int nt = 0; nt < 2; ++nt) {
            int col = (wave << 5) + (nt << 4) + m;
            #pragma unroll
            for (int i = 0; i < 4; ++i) {
                int rr = (mt << 4) + (q << 2) + i;
                float h = acc[mt][nt][i];
                h = h > 0.f ? h : 0.f;
                float lift = bf2f(sA[rr * LDA + col]);
                sA[rr * LDA + 128 + col] = f2bf(e2 * h + lift);
                float hp = __shfl_xor(h, 1);
                if ((m & 1) == 0 && e0 + rr < E) {
                    unsigned pk = (unsigned)f2h(h) | ((unsigned)f2h(hp) << 16);
                    int sn = sSrc[rr], dn = sDst[rr];
                    unsigned long long a0 =
                        (unsigned long long)(lvl + (size_t)sn * H + col);
                    unsigned long long a1 =
                        (unsigned long long)(lvl + (size_t)dn * H + col);
                    asm volatile("global_atomic_pk_add_f16 %0, %1, off"
                                 :: "v"(a0), "v"(pk) : "memory");
                    asm volatile("global_atomic_pk_add_f16 %0, %1, off"
                                 :: "v"(a1), "v"(pk) : "memory");
                }
            }
        }
    }
    light_bar();   // b2 visible; atomics keep flying

    // ---- GEMM2: edge_out = relu(B2 @ W_lift) ----
    f32x4 acc2[4][2];
    #pragma unroll
    for (int mt = 0; mt < 4; ++mt)
        #pragma unroll
        for (int nt = 0; nt < 2; ++nt) acc2[mt][nt] = zero;

    #pragma unroll
    for (int ks = 0; ks < 4; ++ks) {
        int k0 = ks * 32 + q * 8;
        bf16x8 aF[4];
        #pragma unroll
        for (int mt = 0; mt < 4; ++mt)
            aF[mt] = *(const bf16x8*)&sA[(mt * 16 + m) * LDA + 128 + k0];
        bf16x8 bF[2];
        #pragma unroll
        for (int nt = 0; nt < 2; ++nt) {
            int n = (wave << 5) + (nt << 4) + m;
            bF[nt] = *(const bf16x8*)&WLT[n * 128 + k0];
        }
        #pragma unroll
        for (int mt = 0; mt < 4; ++mt)
            #pragma unroll
            for (int nt = 0; nt < 2; ++nt)
                acc2[mt][nt] = __builtin_amdgcn_mfma_f32_16x16x32_bf16(
                    aF[mt], bF[nt], acc2[mt][nt], 0, 0, 0);
    }

    #pragma unroll
    for (int mt = 0; mt < 4; ++mt) {
        #pragma unroll
        for (int nt = 0; nt < 2; ++nt) {
            int col = (wave << 5) + (nt << 4) + m;
            #pragma unroll
            for (int i = 0; i < 4; ++i) {
                int rr = (mt << 4) + (q << 2) + i;
                if (e0 + rr < E) {
                    float v = acc2[mt][nt][i];
                    v = v > 0.f ? v : 0.f;
                    __builtin_nontemporal_store(v, &edge_out[(size_t)(e0 + rr) * H + col]);
                }
            }
        }
    }
}

// ---------------- node kernel ----------------
// node_out = relu(((1+eps1)*node_rep_bf16 + lvl_fp16) @ W2)
__global__ __launch_bounds__(256) void node_kernel(
    const short* __restrict__ NRB, const unsigned short* __restrict__ lvl,
    const short* __restrict__ W2T, const float* __restrict__ eps1p,
    float* __restrict__ node_out, int N)
{
    __shared__ short sA[MB * LDB];

    const int tid = threadIdx.x;
    const int r0  = blockIdx.x * MB;
    const float e1 = 1.f + eps1p[0];

    {
        int row  = tid >> 2;
        int cseg = (tid & 3) << 5;
        int r = r0 + row;
        short* rowA = sA + row * LDB;
        if (r < N) {
            const bf16x8* np = (const bf16x8*)(NRB + (size_t)r * H + cseg);
            const uint2* lp = (const uint2*)(lvl + (size_t)r * H + cseg);
            #pragma unroll
            for (int j = 0; j < 4; ++j) {
                bf16x8 nb = np[j];
                uint2 h0 = lp[2 * j], h1 = lp[2 * j + 1];
                float f[8] = {
                    h2f((unsigned short)(h0.x & 0xFFFF)), h2f((unsigned short)(h0.x >> 16)),
                    h2f((unsigned short)(h0.y & 0xFFFF)), h2f((unsigned short)(h0.y >> 16)),
                    h2f((unsigned short)(h1.x & 0xFFFF)), h2f((unsigned short)(h1.x >> 16)),
                    h2f((unsigned short)(h1.y & 0xFFFF)), h2f((unsigned short)(h1.y >> 16)) };
                bf16x8 o;
                #pragma unroll
                for (int t = 0; t < 8; ++t)
                    o[t] = f2bf(e1 * bf2f(nb[t]) + f[t]);
                *(bf16x8*)&rowA[cseg + 8 * j] = o;
            }
        } else {
            s16x4 z = {0, 0, 0, 0};
            #pragma unroll
            for (int j = 0; j < 8; ++j) *(s16x4*)&rowA[cseg + 4 * j] = z;
        }
    }
    light_bar();

    const int wave = tid >> 6;
    const int lane = tid & 63;
    const int m = lane & 15;
    const int q = lane >> 4;

    f32x4 zero = {0.f, 0.f, 0.f, 0.f};
    f32x4 acc[4][2];
    #pragma unroll
    for (int mt = 0; mt < 4; ++mt)
        #pragma unroll
        for (int nt = 0; nt < 2; ++nt) acc[mt][nt] = zero;

    #pragma unroll
    for (int ks = 0; ks < 4; ++ks) {
        int k0 = ks * 32 + q * 8;
        bf16x8 aF[4];
        #pragma unroll
        for (int mt = 0; mt < 4; ++mt)
            aF[mt] = *(const bf16x8*)&sA[(mt * 16 + m) * LDB + k0];
        bf16x8 bF[2];
        #pragma unroll
        for (int nt = 0; nt < 2; ++nt) {
            int n = (wave << 5) + (nt << 4) + m;
            bF[nt] = *(const bf16x8*)&W2T[n * 128 + k0];
        }
        #pragma unroll
        for (int mt = 0; mt < 4; ++mt)
            #pragma unroll
            for (int nt = 0; nt < 2; ++nt)
                acc[mt][nt] = __builtin_amdgcn_mfma_f32_16x16x32_bf16(
                    aF[mt], bF[nt], acc[mt][nt], 0, 0, 0);
    }

    #pragma unroll
    for (int mt = 0; mt < 4; ++mt) {
        #pragma unroll
        for (int nt = 0; nt < 2; ++nt) {
            int col = (wave << 5) + (nt << 4) + m;
            #pragma unroll
            for (int i = 0; i < 4; ++i) {
                int rr = (mt << 4) + (q << 2) + i;
                if (r0 + rr < N) {
                    float v = acc[mt][nt][i];
                    v = v > 0.f ? v : 0.f;
                    __builtin_nontemporal_store(v, &node_out[(size_t)(r0 + rr) * H + col]);
                }
            }
        }
    }
}

extern "C" void kernel_launch(void* const* d_in, const int* in_sizes, int n_in,
                              void* d_out, int out_size, void* d_ws, size_t ws_size,
                              hipStream_t stream) {
    const float* node_rep = (const float*)d_in[0];
    const float* edge_rep = (const float*)d_in[1];
    const int*   eidx     = (const int*)d_in[2];
    const float* W1       = (const float*)d_in[3];
    const float* W2       = (const float*)d_in[4];
    const float* WL       = (const float*)d_in[5];
    const float* eps1     = (const float*)d_in[6];
    const float* eps2     = (const float*)d_in[7];

    const int N = in_sizes[0] / H;     // 50000
    const int E = in_sizes[1] / H;     // 800000

    float* node_out = (float*)d_out;
    float* edge_out = (float*)d_out + (size_t)N * H;

    // workspace: bf16 weights (128 KB) + fp16 lvl (12.8 MB) + bf16 node_rep (12.8 MB)
    char* ws = (char*)d_ws;
    short* W1T = (short*)ws;                               // 256*128*2 = 64 KB
    short* W2T = (short*)(ws + 65536);                     // 32 KB
    short* WLT = (short*)(ws + 65536 + 32768);             // 32 KB
    unsigned short* lvl = (unsigned short*)(ws + 131072);  // N*H*2 = 12.8 MB
    short* NRB = (short*)(ws + 131072 + (size_t)N * H * 2);

    const int total8 = N * H / 8;      // 800000

    hipMemsetAsync(lvl, 0, (size_t)N * H * sizeof(unsigned short), stream);
    prep_weights<<<128, 256, 0, stream>>>(W1, W2, WL, W1T, W2T, WLT);
    node_prep<<<(total8 + 255) / 256, 256, 0, stream>>>(node_rep, NRB, total8);
    edge_kernel<<<(E + MB - 1) / MB, 256, 0, stream>>>(
        NRB, edge_rep, eidx, W1T, WLT, eps2, lvl, edge_out, E);
    node_kernel<<<(N + MB - 1) / MB, 256, 0, stream>>>(
        NRB, lvl, W2T, eps1, node_out, N);
}

// Round 11
// 475.878 us; speedup vs baseline: 2.1062x; 1.7383x over previous
//
#include <hip/hip_runtime.h>

#define H 128
#define MB 64          // edges (or nodes) per block
#define LDA 264        // LDS row stride (elems) for the [64 x 256] concat tile (+8 pad)
#define LDB 136        // LDS row stride for [64 x 128] tiles (+8 pad)

typedef __attribute__((ext_vector_type(8))) short bf16x8;
typedef __attribute__((ext_vector_type(4))) short s16x4;
typedef __attribute__((ext_vector_type(4))) float f32x4;

__device__ __forceinline__ short f2bf(float f) {
    union { float f; unsigned u; } v; v.f = f;
    unsigned r = v.u + 0x7FFF + ((v.u >> 16) & 1);   // RTNE
    return (short)(r >> 16);
}
__device__ __forceinline__ float bf2f(short s) {
    union { unsigned u; float f; } v;
    v.u = ((unsigned)(unsigned short)s) << 16;
    return v.f;
}
__device__ __forceinline__ unsigned short f2h(float f) {
    union { _Float16 h; unsigned short u; } c;
    c.h = (_Float16)f;                               // v_cvt_f16_f32 (RTNE)
    return c.u;
}
__device__ __forceinline__ float h2f(unsigned short u) {
    union { unsigned short u; _Float16 h; } c;
    c.u = u;
    return (float)c.h;                               // v_cvt_f32_f16
}

// ---------------- weight prep: fp32 [K,N] -> bf16 transposed [N,K] ----------------
__global__ __launch_bounds__(256) void prep_weights(
    const float* __restrict__ W1, const float* __restrict__ W2,
    const float* __restrict__ WL,
    short* __restrict__ W1T, short* __restrict__ W2T, short* __restrict__ WLT)
{
    int tid = blockIdx.x * 256 + threadIdx.x;      // 0..32767
    {   // W1: [256,128] -> W1T [128][256]
        int n = tid >> 8, k = tid & 255;
        W1T[n * 256 + k] = f2bf(W1[k * 128 + n]);
    }
    if (tid < 16384) {  // W2, W_lift: [128,128] -> [128][128]
        int n = tid >> 7, k = tid & 127;
        W2T[n * 128 + k] = f2bf(W2[k * 128 + n]);
        WLT[n * 128 + k] = f2bf(WL[k * 128 + n]);
    }
}

// ---------------- node_rep fp32 -> bf16 copy (halves gather traffic) ----------------
__global__ __launch_bounds__(256) void node_prep(
    const float* __restrict__ node_rep, short* __restrict__ NRB, int total8)
{
    int i = blockIdx.x * 256 + threadIdx.x;        // one per 8 elems
    if (i < total8) {
        const float4* p = (const float4*)(node_rep + (size_t)i * 8);
        float4 a = p[0], b = p[1];
        bf16x8 o = { f2bf(a.x), f2bf(a.y), f2bf(a.z), f2bf(a.w),
                     f2bf(b.x), f2bf(b.y), f2bf(b.z), f2bf(b.w) };
        *(bf16x8*)(NRB + (size_t)i * 8) = o;
    }
}

// ---------------- edge kernel (r3 + row-coalesced scatter) ----------------
// GEMM1: [64,256]x[256,128] -> h; epilogue writes b2 into the dead edge_rep half
// of sA and pk-f16(h) into the dead lift half; then a row-coalesced scatter
// (one full-wave 256B atomic instruction per destination row) fires before
// GEMM2 so the atomics drain under compute + stores.
__global__ __launch_bounds__(256) void edge_kernel(
    const short* __restrict__ NRB, const float* __restrict__ edge_rep,
    const int* __restrict__ eidx,
    const short* __restrict__ W1T, const short* __restrict__ WLT,
    const float* __restrict__ eps2p,
    unsigned short* __restrict__ lvl, float* __restrict__ edge_out, int E)
{
    __shared__ short sA[MB * LDA];   // [64][256]: cols 0..127 lift->pk(h), 128..255 er->b2
    __shared__ int sSrc[MB], sDst[MB];

    const int tid = threadIdx.x;
    const int e0  = blockIdx.x * MB;
    const float e2 = 1.f + eps2p[0];

    // ---- stage: 4 threads per edge row, each covers 32 cols ----
    {
        int row  = tid >> 2;
        int cseg = (tid & 3) << 5;        // 0,32,64,96
        int e = e0 + row;
        int sIdx = 0, dIdx = 0;
        bool ev = (e < E);
        if (ev) { sIdx = eidx[e]; dIdx = eidx[E + e]; }
        if ((tid & 3) == 0) { sSrc[row] = sIdx; sDst[row] = dIdx; }
        short* rowA = sA + row * LDA;
        if (ev) {
            const bf16x8* sp = (const bf16x8*)(NRB + (size_t)sIdx * H + cseg);
            const bf16x8* dp = (const bf16x8*)(NRB + (size_t)dIdx * H + cseg);
            const float4* ep = (const float4*)(edge_rep + (size_t)e * H + cseg);
            #pragma unroll
            for (int j = 0; j < 4; ++j) {
                bf16x8 a = sp[j], b = dp[j];
                bf16x8 lift;
                #pragma unroll
                for (int t = 0; t < 8; ++t)
                    lift[t] = f2bf(bf2f(a[t]) + bf2f(b[t]));
                *(bf16x8*)&rowA[cseg + 8 * j] = lift;
            }
            #pragma unroll
            for (int j = 0; j < 8; ++j) {
                float4 c = ep[j];
                s16x4 er = { f2bf(c.x), f2bf(c.y), f2bf(c.z), f2bf(c.w) };
                *(s16x4*)&rowA[H + cseg + 4 * j] = er;
            }
        } else {
            s16x4 z = {0, 0, 0, 0};
            #pragma unroll
            for (int j = 0; j < 8; ++j) {
                int cc = cseg + 4 * j;
                *(s16x4*)&rowA[cc]     = z;
                *(s16x4*)&rowA[H + cc] = z;
            }
        }
    }
    __syncthreads();

    const int wave = tid >> 6;
    const int lane = tid & 63;
    const int m = lane & 15;     // A row / B col / D col
    const int q = lane >> 4;     // k-quad, D row group

    // ---- GEMM1: wave owns cols [wave*32, wave*32+32), all 64 rows ----
    f32x4 zero = {0.f, 0.f, 0.f, 0.f};
    f32x4 acc[4][2];
    #pragma unroll
    for (int mt = 0; mt < 4; ++mt)
        #pragma unroll
        for (int nt = 0; nt < 2; ++nt) acc[mt][nt] = zero;

    #pragma unroll
    for (int ks = 0; ks < 8; ++ks) {
        int k0 = ks * 32 + q * 8;
        bf16x8 aF[4];
        #pragma unroll
        for (int mt = 0; mt < 4; ++mt)
            aF[mt] = *(const bf16x8*)&sA[(mt * 16 + m) * LDA + k0];
        bf16x8 bF[2];
        #pragma unroll
        for (int nt = 0; nt < 2; ++nt) {
            int n = (wave << 5) + (nt << 4) + m;
            bF[nt] = *(const bf16x8*)&W1T[n * 256 + k0];
        }
        #pragma unroll
        for (int mt = 0; mt < 4; ++mt)
            #pragma unroll
            for (int nt = 0; nt < 2; ++nt)
                acc[mt][nt] = __builtin_amdgcn_mfma_f32_16x16x32_bf16(
                    aF[mt], bF[nt], acc[mt][nt], 0, 0, 0);
    }
    __syncthreads();   // GEMM1 reads of both halves done before overwrites

    // ---- epilogue 1: relu -> h; b2 -> cols 128..255; pk(h) -> cols 0..127 ----
    // Per iteration: all lanes read lift, then shfl, then even lanes overwrite
    // the pair's lift slots with pk — wave-lockstep makes the order safe; rows
    // and col-ranges touched by different (mt,nt) iterations are disjoint.
    #pragma unroll
    for (int mt = 0; mt < 4; ++mt) {
        #pragma unroll
        for (int nt = 0; nt < 2; ++nt) {
            int col = (wave << 5) + (nt << 4) + m;
            #pragma unroll
            for (int i = 0; i < 4; ++i) {
                int rr = (mt << 4) + (q << 2) + i;
                float h = acc[mt][nt][i];
                h = h > 0.f ? h : 0.f;
                float lift = bf2f(sA[rr * LDA + col]);
                sA[rr * LDA + 128 + col] = f2bf(e2 * h + lift);
                float hp = __shfl_xor(h, 1);
                if ((m & 1) == 0) {
                    unsigned pk = (unsigned)f2h(h) | ((unsigned)f2h(hp) << 16);
                    *(unsigned*)&sA[rr * LDA + col] = pk;   // pk(h) in lift slot
                }
            }
        }
    }
    __syncthreads();

    // ---- row-coalesced scatter: one full-wave atomic per destination row ----
    // d in [0,128): edge row d>>1, endpoint d&1. Lane covers cols {2*lane,2*lane+1}
    // -> 64 lanes x 4B = 256B contiguous at the destination (4 full sectors).
    #pragma unroll 4
    for (int it = 0; it < 32; ++it) {
        int d   = (it << 2) + wave;
        int er_ = d >> 1;
        if (e0 + er_ < E) {
            int node = (d & 1) ? sDst[er_] : sSrc[er_];
            unsigned pk = *(const unsigned*)&sA[er_ * LDA + lane * 2];
            unsigned long long a0 =
                (unsigned long long)(lvl + (size_t)node * H + lane * 2);
            asm volatile("global_atomic_pk_add_f16 %0, %1, off"
                         :: "v"(a0), "v"(pk) : "memory");
        }
    }

    // ---- GEMM2: edge_out = relu(B2 @ W_lift)  (atomics drain underneath) ----
    f32x4 acc2[4][2];
    #pragma unroll
    for (int mt = 0; mt < 4; ++mt)
        #pragma unroll
        for (int nt = 0; nt < 2; ++nt) acc2[mt][nt] = zero;

    #pragma unroll
    for (int ks = 0; ks < 4; ++ks) {
        int k0 = ks * 32 + q * 8;
        bf16x8 aF[4];
        #pragma unroll
        for (int mt = 0; mt < 4; ++mt)
            aF[mt] = *(const bf16x8*)&sA[(mt * 16 + m) * LDA + 128 + k0];
        bf16x8 bF[2];
        #pragma unroll
        for (int nt = 0; nt < 2; ++nt) {
            int n = (wave << 5) + (nt << 4) + m;
            bF[nt] = *(const bf16x8*)&WLT[n * 128 + k0];
        }
        #pragma unroll
        for (int mt = 0; mt < 4; ++mt)
            #pragma unroll
            for (int nt = 0; nt < 2; ++nt)
                acc2[mt][nt] = __builtin_amdgcn_mfma_f32_16x16x32_bf16(
                    aF[mt], bF[nt], acc2[mt][nt], 0, 0, 0);
    }

    #pragma unroll
    for (int mt = 0; mt < 4; ++mt) {
        #pragma unroll
        for (int nt = 0; nt < 2; ++nt) {
            int col = (wave << 5) + (nt << 4) + m;
            #pragma unroll
            for (int i = 0; i < 4; ++i) {
                int rr = (mt << 4) + (q << 2) + i;
                if (e0 + rr < E) {
                    float v = acc2[mt][nt][i];
                    edge_out[(size_t)(e0 + rr) * H + col] = v > 0.f ? v : 0.f;
                }
            }
        }
    }
}

// ---------------- node kernel ----------------
// node_out = relu(((1+eps1)*node_rep_bf16 + lvl_fp16) @ W2)
__global__ __launch_bounds__(256) void node_kernel(
    const short* __restrict__ NRB, const unsigned short* __restrict__ lvl,
    const short* __restrict__ W2T, const float* __restrict__ eps1p,
    float* __restrict__ node_out, int N)
{
    __shared__ short sA[MB * LDB];

    const int tid = threadIdx.x;
    const int r0  = blockIdx.x * MB;
    const float e1 = 1.f + eps1p[0];

    {
        int row  = tid >> 2;
        int cseg = (tid & 3) << 5;
        int r = r0 + row;
        short* rowA = sA + row * LDB;
        if (r < N) {
            const bf16x8* np = (const bf16x8*)(NRB + (size_t)r * H + cseg);
            const uint2* lp = (const uint2*)(lvl + (size_t)r * H + cseg);
            #pragma unroll
            for (int j = 0; j < 4; ++j) {
                bf16x8 nb = np[j];
                uint2 h0 = lp[2 * j], h1 = lp[2 * j + 1];
                float f[8] = {
                    h2f((unsigned short)(h0.x & 0xFFFF)), h2f((unsigned short)(h0.x >> 16)),
                    h2f((unsigned short)(h0.y & 0xFFFF)), h2f((unsigned short)(h0.y >> 16)),
                    h2f((unsigned short)(h1.x & 0xFFFF)), h2f((unsigned short)(h1.x >> 16)),
                    h2f((unsigned short)(h1.y & 0xFFFF)), h2f((unsigned short)(h1.y >> 16)) };
                bf16x8 o;
                #pragma unroll
                for (int t = 0; t < 8; ++t)
                    o[t] = f2bf(e1 * bf2f(nb[t]) + f[t]);
                *(bf16x8*)&rowA[cseg + 8 * j] = o;
            }
        } else {
            s16x4 z = {0, 0, 0, 0};
            #pragma unroll
            for (int j = 0; j < 8; ++j) *(s16x4*)&rowA[cseg + 4 * j] = z;
        }
    }
    __syncthreads();

    const int wave = tid >> 6;
    const int lane = tid & 63;
    const int m = lane & 15;
    const int q = lane >> 4;

    f32x4 zero = {0.f, 0.f, 0.f, 0.f};
    f32x4 acc[4][2];
    #pragma unroll
    for (int mt = 0; mt < 4; ++mt)
        #pragma unroll
        for (int nt = 0; nt < 2; ++nt) acc[mt][nt] = zero;

    #pragma unroll
    for (int ks = 0; ks < 4; ++ks) {
        int k0 = ks * 32 + q * 8;
        bf16x8 aF[4];
        #pragma unroll
        for (int mt = 0; mt < 4; ++mt)
            aF[mt] = *(const bf16x8*)&sA[(mt * 16 + m) * LDB + k0];
        bf16x8 bF[2];
        #pragma unroll
        for (int nt = 0; nt < 2; ++nt) {
            int n = (wave << 5) + (nt << 4) + m;
            bF[nt] = *(const bf16x8*)&W2T[n * 128 + k0];
        }
        #pragma unroll
        for (int mt = 0; mt < 4; ++mt)
            #pragma unroll
            for (int nt = 0; nt < 2; ++nt)
                acc[mt][nt] = __builtin_amdgcn_mfma_f32_16x16x32_bf16(
                    aF[mt], bF[nt], acc[mt][nt], 0, 0, 0);
    }

    #pragma unroll
    for (int mt = 0; mt < 4; ++mt) {
        #pragma unroll
        for (int nt = 0; nt < 2; ++nt) {
            int col = (wave << 5) + (nt << 4) + m;
            #pragma unroll
            for (int i = 0; i < 4; ++i) {
                int rr = (mt << 4) + (q << 2) + i;
                if (r0 + rr < N) {
                    float v = acc[mt][nt][i];
                    node_out[(size_t)(r0 + rr) * H + col] = v > 0.f ? v : 0.f;
                }
            }
        }
    }
}

extern "C" void kernel_launch(void* const* d_in, const int* in_sizes, int n_in,
                              void* d_out, int out_size, void* d_ws, size_t ws_size,
                              hipStream_t stream) {
    const float* node_rep = (const float*)d_in[0];
    const float* edge_rep = (const float*)d_in[1];
    const int*   eidx     = (const int*)d_in[2];
    const float* W1       = (const float*)d_in[3];
    const float* W2       = (const float*)d_in[4];
    const float* WL       = (const float*)d_in[5];
    const float* eps1     = (const float*)d_in[6];
    const float* eps2     = (const float*)d_in[7];

    const int N = in_sizes[0] / H;     // 50000
    const int E = in_sizes[1] / H;     // 800000

    float* node_out = (float*)d_out;
    float* edge_out = (float*)d_out + (size_t)N * H;

    // workspace: bf16 weights (128 KB) + fp16 lvl (12.8 MB) + bf16 node_rep (12.8 MB)
    char* ws = (char*)d_ws;
    short* W1T = (short*)ws;                               // 256*128*2 = 64 KB
    short* W2T = (short*)(ws + 65536);                     // 32 KB
    short* WLT = (short*)(ws + 65536 + 32768);             // 32 KB
    unsigned short* lvl = (unsigned short*)(ws + 131072);  // N*H*2 = 12.8 MB
    short* NRB = (short*)(ws + 131072 + (size_t)N * H * 2);

    const int total8 = N * H / 8;      // 800000

    hipMemsetAsync(lvl, 0, (size_t)N * H * sizeof(unsigned short), stream);
    prep_weights<<<128, 256, 0, stream>>>(W1, W2, WL, W1T, W2T, WLT);
    node_prep<<<(total8 + 255) / 256, 256, 0, stream>>>(node_rep, NRB, total8);
    edge_kernel<<<(E + MB - 1) / MB, 256, 0, stream>>>(
        NRB, edge_rep, eidx, W1T, WLT, eps2, lvl, edge_out, E);
    node_kernel<<<(N + MB - 1) / MB, 256, 0, stream>>>(
        NRB, lvl, W2T, eps1, node_out, N);
}